// Round 6
// baseline (405.398 us; speedup 1.0000x reference)
//
#include <hip/hip_runtime.h>
#include <hip/hip_fp16.h>
#include <hip/hip_bf16.h>

// PGNN layer for MI355X (gfx950).
//   u = feature @ W_u + b_u            [N,64]
//   v = feature @ W_v + b_v            [N,64]
//   msg[e] = v[dst[e]] + u[src[e]] * sp_dist[e]
//   msgs = relu(msg[anchor_eid]).reshape(N, K, 64)
//   out_position  = msgs @ W_out + b_out   -> [N,K]
//   out_structure = mean_k(msgs)           -> [N,64]
// N=50000, K=64, E=N*K=3.2M. d_out = out_position ++ out_structure.
//
// R5 (resubmitted after infra failure): dim-sliced edge passes.
// Evidence R1/R3/R4: TCC-fetch pinned at 3.6 TB/s across 3 schedules,
// time = fetched_bytes/3.6TB/s -> L2-miss-throughput-bound (uv 12.8 MB >
// 4 MiB per-XCD L2 -> random gathers always miss). Fix: 4 passes over
// 16-dim slices; per-pass table = 3.2 MB -> L2-resident -> gathers hit.
// Pass 0 packs (src,dst,sp16) into 8 B/anchor; passes 1-3 stream it (NT).
// out_pos accumulated with one deterministic atomicAdd/element/pass.

#define IN_DIM 256
#define OUT_DIM 64
#define KANCH 64

// ---------------- Kernel 1: fused projection GEMM (fp32 -> fp16 uvT) -------
// uvT[4][N][32]: slice q holds u dims 16q..16q+15 at [0..15], v at [16..31].
__global__ __launch_bounds__(128) void pgnn_proj_kernel(
    const float* __restrict__ feature,
    const float* __restrict__ Wu, const float* __restrict__ bu,
    const float* __restrict__ Wv, const float* __restrict__ bv,
    __half* __restrict__ uvT, int N)
{
    constexpr int BM = 64, BK = 16, PA = 68, PB = 132;
    __shared__ float sA[BK * PA];   // sA[k][m], transposed A tile
    __shared__ float sB[BK * PB];   // sB[k][c]

    const int tid  = threadIdx.x;
    const int row0 = blockIdx.x * BM;
    const int tr   = tid >> 4;   // 0..7 -> rows tr*8..tr*8+7
    const int tc   = tid & 15;   // 0..15 -> cols tc*8..tc*8+7

    float acc[8][8];
    #pragma unroll
    for (int i = 0; i < 8; ++i)
        #pragma unroll
        for (int j = 0; j < 8; ++j) acc[i][j] = 0.f;

    for (int k0 = 0; k0 < IN_DIM; k0 += BK) {
        #pragma unroll
        for (int i = 0; i < 2; ++i) {
            int f  = tid + i * 128;        // 0..255
            int m  = f >> 2, c4 = f & 3;
            int gr = row0 + m;
            float4 va = make_float4(0.f, 0.f, 0.f, 0.f);
            if (gr < N)
                va = *reinterpret_cast<const float4*>(
                        &feature[(size_t)gr * IN_DIM + k0 + c4 * 4]);
            sA[(c4 * 4 + 0) * PA + m] = va.x;
            sA[(c4 * 4 + 1) * PA + m] = va.y;
            sA[(c4 * 4 + 2) * PA + m] = va.z;
            sA[(c4 * 4 + 3) * PA + m] = va.w;
        }
        #pragma unroll
        for (int i = 0; i < 4; ++i) {
            int f  = tid + i * 128;        // 0..511
            int kk = f >> 5, c4 = f & 31;
            float4 vb;
            if (c4 < 16)
                vb = *reinterpret_cast<const float4*>(&Wu[(k0 + kk) * OUT_DIM + c4 * 4]);
            else
                vb = *reinterpret_cast<const float4*>(&Wv[(k0 + kk) * OUT_DIM + (c4 - 16) * 4]);
            *reinterpret_cast<float4*>(&sB[kk * PB + c4 * 4]) = vb;
        }
        __syncthreads();

        #pragma unroll
        for (int k = 0; k < BK; ++k) {
            float4 a0 = *reinterpret_cast<const float4*>(&sA[k * PA + tr * 8]);
            float4 a1 = *reinterpret_cast<const float4*>(&sA[k * PA + tr * 8 + 4]);
            float4 b0 = *reinterpret_cast<const float4*>(&sB[k * PB + tc * 8]);
            float4 b1 = *reinterpret_cast<const float4*>(&sB[k * PB + tc * 8 + 4]);
            float a[8] = {a0.x, a0.y, a0.z, a0.w, a1.x, a1.y, a1.z, a1.w};
            float b[8] = {b0.x, b0.y, b0.z, b0.w, b1.x, b1.y, b1.z, b1.w};
            #pragma unroll
            for (int i = 0; i < 8; ++i)
                #pragma unroll
                for (int j = 0; j < 8; ++j)
                    acc[i][j] = fmaf(a[i], b[j], acc[i][j]);
        }
        __syncthreads();
    }

    // Epilogue -> uvT slices. cols c = tc*8+j: half=tc>>3, q=(tc>>1)&3,
    // slice offset = half*16 + (tc&1)*8 + j.
    const int q    = (tc >> 1) & 3;
    const int half = tc >> 3;
    const int j0   = (tc & 1) * 8;
    #pragma unroll
    for (int i = 0; i < 8; ++i) {
        int gr = row0 + tr * 8 + i;
        if (gr >= N) continue;
        __half* dstp = uvT + ((size_t)q * N + gr) * 32 + half * 16 + j0;
        #pragma unroll
        for (int j = 0; j < 8; j += 2) {
            int c0 = tc * 8 + j;
            float bias0 = (c0 < OUT_DIM) ? bu[c0] : bv[c0 - OUT_DIM];
            float bias1 = (c0 + 1 < OUT_DIM) ? bu[c0 + 1] : bv[c0 + 1 - OUT_DIM];
            __half2 h = __floats2half2_rn(acc[i][j] + bias0, acc[i][j + 1] + bias1);
            *reinterpret_cast<__half2*>(dstp + j) = h;
        }
    }
}

// ---------------- Kernel 2: dim-sliced edge pass ---------------------------
// One 64-lane wave per node, 4 waves/block. lane = (g = lane>>4, j = lane&15).
// Pass q covers dims 16q..16q+15. Group g handles anchors k = i*4+g, i=0..15.
// GATHER: meta via anchor_eid->src/dst/sp (pass 0 / fallback); else from the
// packed 8B stream. WPACK: write packed stream. STOREPOS: store pos+bo (else
// atomicAdd the partial).
template<bool GATHER, bool WPACK, bool STOREPOS>
__global__ __launch_bounds__(256) void pgnn_pass_kernel(
    const __half* __restrict__ uvT,
    const int*    __restrict__ src,
    const int*    __restrict__ dst,
    const float*  __restrict__ sp_dist,
    const int*    __restrict__ aeid,
    unsigned long long* __restrict__ packed,
    const float*  __restrict__ W_out,
    const float*  __restrict__ b_out,
    float* __restrict__ out_pos,     // [N,64]
    float* __restrict__ out_struct,  // [N,64]
    int N, int q)
{
    const int lane = threadIdx.x & 63;
    const int wv   = threadIdx.x >> 6;
    const int n    = blockIdx.x * 4 + wv;
    if (n >= N) return;   // wave-uniform; no block-wide syncs below

    __shared__ float tile[4][64 * 17];
    float* t = tile[wv];

    const int j = lane & 15, g = lane >> 4;

    // Per-lane meta for anchor k = lane.
    int ms = 0, md = 0; float msp = 0.f;
    unsigned int mlo = 0, mhi = 0;
    if constexpr (GATHER) {
        const int e = __builtin_nontemporal_load(&aeid[(size_t)n * KANCH + lane]);
        ms = src[e]; md = dst[e]; msp = sp_dist[e];
        if constexpr (WPACK) {
            unsigned long long pk =
                  (unsigned long long)(unsigned)ms
                | ((unsigned long long)(unsigned)md << 17)
                | ((unsigned long long)__half_as_ushort(__float2half_rn(msp)) << 34);
            __builtin_nontemporal_store(pk, &packed[(size_t)n * KANCH + lane]);
        }
    } else {
        unsigned long long pk =
            __builtin_nontemporal_load(&packed[(size_t)n * KANCH + lane]);
        mlo = (unsigned int)pk;
        mhi = (unsigned int)(pk >> 32);
    }

    const float w = W_out[q * 16 + j];
    const __half* Uq = uvT + (size_t)q * N * 32;

    float sacc = 0.f;
    float pp[16];

    #pragma unroll
    for (int i = 0; i < 16; ++i) {
        const int k = i * 4 + g;   // source lane for this anchor's meta
        int ss, dd; float sp;
        if constexpr (GATHER) {
            ss = __shfl(ms, k);
            dd = __shfl(md, k);
            sp = __shfl(msp, k);
        } else {
            unsigned int lo = (unsigned int)__shfl((int)mlo, k);
            unsigned int hi = (unsigned int)__shfl((int)mhi, k);
            ss = (int)(lo & 0x1FFFFu);
            dd = (int)(((lo >> 17) | (hi << 15)) & 0x1FFFFu);
            sp = __half2float(__ushort_as_half((unsigned short)((hi >> 2) & 0xFFFFu)));
        }
        const float u = __half2float(Uq[(size_t)ss * 32 + j]);
        const float v = __half2float(Uq[(size_t)dd * 32 + 16 + j]);
        float m = fmaxf(fmaf(u, sp, v), 0.f);
        sacc += m;
        pp[i] = m * w;
    }

    // pos partial: transpose via LDS, then sum 16 dims per anchor.
    #pragma unroll
    for (int i = 0; i < 16; ++i)
        t[(i * 4 + g) * 17 + j] = pp[i];
    asm volatile("s_waitcnt lgkmcnt(0)" ::: "memory");

    float pos = 0.f;
    #pragma unroll
    for (int jj = 0; jj < 16; ++jj)
        pos += t[lane * 17 + jj];

    if constexpr (STOREPOS) {
        const float bo = b_out[0];
        __builtin_nontemporal_store(pos + bo, &out_pos[(size_t)n * KANCH + lane]);
    } else {
        atomicAdd(&out_pos[(size_t)n * KANCH + lane], pos);
    }

    // struct: sum over the 4 g-groups at fixed j; lanes 0..15 hold totals.
    float s2 = sacc;
    s2 += __shfl_xor(s2, 16);
    s2 += __shfl_xor(s2, 32);
    if (lane < 16)
        __builtin_nontemporal_store(s2 * (1.f / (float)KANCH),
                                    &out_struct[(size_t)n * OUT_DIM + q * 16 + lane]);
}

extern "C" void kernel_launch(void* const* d_in, const int* in_sizes, int n_in,
                              void* d_out, int out_size, void* d_ws, size_t ws_size,
                              hipStream_t stream) {
    const float* feature    = (const float*)d_in[0];
    const int*   src        = (const int*)  d_in[1];
    const int*   dst        = (const int*)  d_in[2];
    const float* sp_dist    = (const float*)d_in[3];
    const int*   anchor_eid = (const int*)  d_in[4];
    // d_in[5] = dists_max: shape-only in the reference, numerically unused.
    const float* W_u   = (const float*)d_in[6];
    const float* b_u   = (const float*)d_in[7];
    const float* W_v   = (const float*)d_in[8];
    const float* b_v   = (const float*)d_in[9];
    const float* W_out = (const float*)d_in[10];
    const float* b_out = (const float*)d_in[11];

    const int N = in_sizes[0] / IN_DIM;           // 50000

    __half* uvT = (__half*)d_ws;                  // [4][N][32] fp16, 12.8 MB
    size_t uvT_bytes   = (size_t)N * 128 * sizeof(__half);
    size_t packed_off  = (uvT_bytes + 255) & ~(size_t)255;
    unsigned long long* packed =
        (unsigned long long*)((char*)d_ws + packed_off);
    const bool use_packed =
        (ws_size >= packed_off + (size_t)N * KANCH * 8) && (N < (1 << 17));

    float* out_pos    = (float*)d_out;            // [N,K]
    float* out_struct = (float*)d_out + (size_t)N * KANCH;

    {
        constexpr int BM = 64;
        dim3 grid((N + BM - 1) / BM);
        pgnn_proj_kernel<<<grid, 128, 0, stream>>>(feature, W_u, b_u, W_v, b_v, uvT, N);
    }
    dim3 pgrid((N + 3) / 4);
    if (use_packed) {
        pgnn_pass_kernel<true, true, true><<<pgrid, 256, 0, stream>>>(
            uvT, src, dst, sp_dist, anchor_eid, packed, W_out, b_out,
            out_pos, out_struct, N, 0);
        for (int q = 1; q < 4; ++q)
            pgnn_pass_kernel<false, false, false><<<pgrid, 256, 0, stream>>>(
                uvT, src, dst, sp_dist, anchor_eid, packed, W_out, b_out,
                out_pos, out_struct, N, q);
    } else {
        pgnn_pass_kernel<true, false, true><<<pgrid, 256, 0, stream>>>(
            uvT, src, dst, sp_dist, anchor_eid, packed, W_out, b_out,
            out_pos, out_struct, N, 0);
        for (int q = 1; q < 4; ++q)
            pgnn_pass_kernel<true, false, false><<<pgrid, 256, 0, stream>>>(
                uvT, src, dst, sp_dist, anchor_eid, packed, W_out, b_out,
                out_pos, out_struct, N, q);
    }
}

// Round 8
// 289.739 us; speedup vs baseline: 1.3992x; 1.3992x over previous
//
#include <hip/hip_runtime.h>
#include <hip/hip_fp16.h>
#include <hip/hip_bf16.h>

// PGNN layer for MI355X (gfx950).
//   u = feature @ W_u + b_u            [N,64]
//   v = feature @ W_v + b_v            [N,64]
//   msg[e] = v[dst[e]] + u[src[e]] * sp_dist[e]
//   msgs = relu(msg[anchor_eid]).reshape(N, K, 64)
//   out_position  = msgs @ W_out + b_out   -> [N,K]
//   out_structure = mean_k(msgs)           -> [N,64]
// N=50000, K=64, E=N*K=3.2M. d_out = out_position ++ out_structure.
//
// R8 = R7 with the float4 nontemporal-store compile error fixed (ext_vector).
// R7 structure (evidence R6: dim-sliced passes ~40us each = L2-resident WIN;
// pass 0 = 221us/781MB = meta-gather thrash through 3 separate arrays):
//   1. proj GEMM -> uvT[4][N][32] fp16 (unchanged)
//   2. merge: stream (src,dst,sp16) -> edge_meta[E] 8B records  (~18us)
//   3. pack: packed[i] = edge_meta[aeid[i]] - ONE line-miss/anchor (~55us)
//   4. 4 symmetric dim-slice passes, half4 gathers, tiny LDS      (~4x32us)

#define IN_DIM 256
#define OUT_DIM 64
#define KANCH 64

typedef float vfloat4 __attribute__((ext_vector_type(4)));

// ---------------- Kernel 1: fused projection GEMM (fp32 -> fp16 uvT) -------
// uvT[4][N][32]: slice q holds u dims 16q..16q+15 at [0..15], v at [16..31].
__global__ __launch_bounds__(128) void pgnn_proj_kernel(
    const float* __restrict__ feature,
    const float* __restrict__ Wu, const float* __restrict__ bu,
    const float* __restrict__ Wv, const float* __restrict__ bv,
    __half* __restrict__ uvT, int N)
{
    constexpr int BM = 64, BK = 16, PA = 68, PB = 132;
    __shared__ float sA[BK * PA];   // sA[k][m], transposed A tile
    __shared__ float sB[BK * PB];   // sB[k][c]

    const int tid  = threadIdx.x;
    const int row0 = blockIdx.x * BM;
    const int tr   = tid >> 4;   // 0..7 -> rows tr*8..tr*8+7
    const int tc   = tid & 15;   // 0..15 -> cols tc*8..tc*8+7

    float acc[8][8];
    #pragma unroll
    for (int i = 0; i < 8; ++i)
        #pragma unroll
        for (int j = 0; j < 8; ++j) acc[i][j] = 0.f;

    for (int k0 = 0; k0 < IN_DIM; k0 += BK) {
        #pragma unroll
        for (int i = 0; i < 2; ++i) {
            int f  = tid + i * 128;        // 0..255
            int m  = f >> 2, c4 = f & 3;
            int gr = row0 + m;
            float4 va = make_float4(0.f, 0.f, 0.f, 0.f);
            if (gr < N)
                va = *reinterpret_cast<const float4*>(
                        &feature[(size_t)gr * IN_DIM + k0 + c4 * 4]);
            sA[(c4 * 4 + 0) * PA + m] = va.x;
            sA[(c4 * 4 + 1) * PA + m] = va.y;
            sA[(c4 * 4 + 2) * PA + m] = va.z;
            sA[(c4 * 4 + 3) * PA + m] = va.w;
        }
        #pragma unroll
        for (int i = 0; i < 4; ++i) {
            int f  = tid + i * 128;        // 0..511
            int kk = f >> 5, c4 = f & 31;
            float4 vb;
            if (c4 < 16)
                vb = *reinterpret_cast<const float4*>(&Wu[(k0 + kk) * OUT_DIM + c4 * 4]);
            else
                vb = *reinterpret_cast<const float4*>(&Wv[(k0 + kk) * OUT_DIM + (c4 - 16) * 4]);
            *reinterpret_cast<float4*>(&sB[kk * PB + c4 * 4]) = vb;
        }
        __syncthreads();

        #pragma unroll
        for (int k = 0; k < BK; ++k) {
            float4 a0 = *reinterpret_cast<const float4*>(&sA[k * PA + tr * 8]);
            float4 a1 = *reinterpret_cast<const float4*>(&sA[k * PA + tr * 8 + 4]);
            float4 b0 = *reinterpret_cast<const float4*>(&sB[k * PB + tc * 8]);
            float4 b1 = *reinterpret_cast<const float4*>(&sB[k * PB + tc * 8 + 4]);
            float a[8] = {a0.x, a0.y, a0.z, a0.w, a1.x, a1.y, a1.z, a1.w};
            float b[8] = {b0.x, b0.y, b0.z, b0.w, b1.x, b1.y, b1.z, b1.w};
            #pragma unroll
            for (int i = 0; i < 8; ++i)
                #pragma unroll
                for (int j = 0; j < 8; ++j)
                    acc[i][j] = fmaf(a[i], b[j], acc[i][j]);
        }
        __syncthreads();
    }

    // Epilogue -> uvT slices. cols c = tc*8+j: half=tc>>3, q=(tc>>1)&3.
    const int q    = (tc >> 1) & 3;
    const int half = tc >> 3;
    const int j0   = (tc & 1) * 8;
    #pragma unroll
    for (int i = 0; i < 8; ++i) {
        int gr = row0 + tr * 8 + i;
        if (gr >= N) continue;
        __half* dstp = uvT + ((size_t)q * N + gr) * 32 + half * 16 + j0;
        #pragma unroll
        for (int j = 0; j < 8; j += 2) {
            int c0 = tc * 8 + j;
            float bias0 = (c0 < OUT_DIM) ? bu[c0] : bv[c0 - OUT_DIM];
            float bias1 = (c0 + 1 < OUT_DIM) ? bu[c0 + 1] : bv[c0 + 1 - OUT_DIM];
            __half2 h = __floats2half2_rn(acc[i][j] + bias0, acc[i][j + 1] + bias1);
            *reinterpret_cast<__half2*>(dstp + j) = h;
        }
    }
}

// ---------------- Kernel 2: merge (src,dst,sp16) -> edge_meta[E] 8B --------
// pk = src | dst<<17 | half(sp)<<34   (requires node ids < 2^17)
__global__ __launch_bounds__(256) void pgnn_merge_kernel(
    const int* __restrict__ src, const int* __restrict__ dst,
    const float* __restrict__ sp, unsigned long long* __restrict__ meta, int E)
{
    int i = blockIdx.x * 256 + threadIdx.x;
    if (i >= E) return;
    unsigned long long pk =
          (unsigned long long)(unsigned)__builtin_nontemporal_load(&src[i])
        | ((unsigned long long)(unsigned)__builtin_nontemporal_load(&dst[i]) << 17)
        | ((unsigned long long)__half_as_ushort(
               __float2half_rn(__builtin_nontemporal_load(&sp[i]))) << 34);
    __builtin_nontemporal_store(pk, &meta[i]);
}

// ---------------- Kernel 3: pack: packed[i] = edge_meta[aeid[i]] -----------
__global__ __launch_bounds__(256) void pgnn_pack_kernel(
    const int* __restrict__ aeid, const unsigned long long* __restrict__ meta,
    unsigned long long* __restrict__ packed, int M)
{
    int i = blockIdx.x * 256 + threadIdx.x;
    if (i >= M) return;
    int e = __builtin_nontemporal_load(&aeid[i]);
    __builtin_nontemporal_store(meta[e], &packed[i]);
}

// ---------------- Kernel 4: dim-sliced edge pass ---------------------------
// One wave per node, 4 waves/block. lane = (g = lane>>2 in 0..15, j4 = lane&3).
// Anchor k = i*16+g (i=0..3); lane covers dims q*16 + 4*j4 .. +3 via half4
// gathers. pos: dot over 4 dims + shfl_xor(1,2) over the j4 quad -> LDS ->
// coalesced store/atomic. struct: shfl_xor(4,8,16,32) over g.
// GATHER variant (fallback, any N): reads aeid->src/dst/sp directly.
template<bool GATHER, bool FIRST>
__global__ __launch_bounds__(256) void pgnn_pass_kernel(
    const __half* __restrict__ uvT,
    const int*    __restrict__ src,
    const int*    __restrict__ dst,
    const float*  __restrict__ sp_dist,
    const int*    __restrict__ aeid,
    const unsigned long long* __restrict__ packed,
    const float*  __restrict__ W_out,
    const float*  __restrict__ b_out,
    float* __restrict__ out_pos,     // [N,64]
    float* __restrict__ out_struct,  // [N,64]
    int N, int q)
{
    const int lane = threadIdx.x & 63;
    const int wv   = threadIdx.x >> 6;
    const int n    = blockIdx.x * 4 + wv;
    if (n >= N) return;   // wave-uniform

    __shared__ float posb[4][64];
    float* pb = posb[wv];

    const int j4 = lane & 3, g = lane >> 2;

    // Per-lane meta for anchor k = lane.
    int ms = 0, md = 0; float msp = 0.f;
    unsigned int mlo = 0, mhi = 0;
    if constexpr (GATHER) {
        const int e = __builtin_nontemporal_load(&aeid[(size_t)n * KANCH + lane]);
        ms = src[e]; md = dst[e]; msp = sp_dist[e];
    } else {
        unsigned long long pk =
            __builtin_nontemporal_load(&packed[(size_t)n * KANCH + lane]);
        mlo = (unsigned int)pk;
        mhi = (unsigned int)(pk >> 32);
    }

    const float4 w4 = *reinterpret_cast<const float4*>(&W_out[q * 16 + 4 * j4]);
    const __half* Uq = uvT + (size_t)q * N * 32;

    float4 acc = make_float4(0.f, 0.f, 0.f, 0.f);
    union H4 { uint2 u; __half2 h[2]; };

    #pragma unroll
    for (int i = 0; i < 4; ++i) {
        const int k = i * 16 + g;   // anchor index; meta source lane
        int ss, dd; float sp;
        if constexpr (GATHER) {
            ss = __shfl(ms, k);
            dd = __shfl(md, k);
            sp = __shfl(msp, k);
        } else {
            unsigned int lo = (unsigned int)__shfl((int)mlo, k);
            unsigned int hi = (unsigned int)__shfl((int)mhi, k);
            ss = (int)(lo & 0x1FFFFu);
            dd = (int)(((lo >> 17) | (hi << 15)) & 0x1FFFFu);
            sp = __half2float(__ushort_as_half((unsigned short)((hi >> 2) & 0xFFFFu)));
        }
        H4 uu, vv;
        uu.u = *reinterpret_cast<const uint2*>(&Uq[(size_t)ss * 32 + 4 * j4]);
        vv.u = *reinterpret_cast<const uint2*>(&Uq[(size_t)dd * 32 + 16 + 4 * j4]);
        float2 ua = __half22float2(uu.h[0]), ub = __half22float2(uu.h[1]);
        float2 va = __half22float2(vv.h[0]), vb = __half22float2(vv.h[1]);
        float m0 = fmaxf(fmaf(ua.x, sp, va.x), 0.f);
        float m1 = fmaxf(fmaf(ua.y, sp, va.y), 0.f);
        float m2 = fmaxf(fmaf(ub.x, sp, vb.x), 0.f);
        float m3 = fmaxf(fmaf(ub.y, sp, vb.y), 0.f);
        acc.x += m0; acc.y += m1; acc.z += m2; acc.w += m3;

        // pos partial for anchor k: dot over this lane's 4 dims, then the quad
        float p = fmaf(m0, w4.x, fmaf(m1, w4.y, fmaf(m2, w4.z, m3 * w4.w)));
        p += __shfl_xor(p, 1);
        p += __shfl_xor(p, 2);
        if (j4 == 0) pb[k] = p;
    }
    asm volatile("s_waitcnt lgkmcnt(0)" ::: "memory");

    const float pos = pb[lane];
    if constexpr (FIRST) {
        __builtin_nontemporal_store(pos + b_out[0],
                                    &out_pos[(size_t)n * KANCH + lane]);
    } else {
        atomicAdd(&out_pos[(size_t)n * KANCH + lane], pos);
    }

    // struct: sum acc over the 16 g-groups (lanes stride 4).
    #pragma unroll
    for (int off = 4; off <= 32; off <<= 1) {
        acc.x += __shfl_xor(acc.x, off);
        acc.y += __shfl_xor(acc.y, off);
        acc.z += __shfl_xor(acc.z, off);
        acc.w += __shfl_xor(acc.w, off);
    }
    if (lane < 4) {
        vfloat4 s = { acc.x * (1.f / KANCH), acc.y * (1.f / KANCH),
                      acc.z * (1.f / KANCH), acc.w * (1.f / KANCH) };
        __builtin_nontemporal_store(
            s, reinterpret_cast<vfloat4*>(
                   &out_struct[(size_t)n * OUT_DIM + q * 16 + 4 * lane]));
    }
}

extern "C" void kernel_launch(void* const* d_in, const int* in_sizes, int n_in,
                              void* d_out, int out_size, void* d_ws, size_t ws_size,
                              hipStream_t stream) {
    const float* feature    = (const float*)d_in[0];
    const int*   src        = (const int*)  d_in[1];
    const int*   dst        = (const int*)  d_in[2];
    const float* sp_dist    = (const float*)d_in[3];
    const int*   anchor_eid = (const int*)  d_in[4];
    // d_in[5] = dists_max: shape-only in the reference, numerically unused.
    const float* W_u   = (const float*)d_in[6];
    const float* b_u   = (const float*)d_in[7];
    const float* W_v   = (const float*)d_in[8];
    const float* b_v   = (const float*)d_in[9];
    const float* W_out = (const float*)d_in[10];
    const float* b_out = (const float*)d_in[11];

    const int N = in_sizes[0] / IN_DIM;           // 50000
    const int E = in_sizes[1];                    // 3.2M
    const int M = N * KANCH;                      // anchors

    __half* uvT = (__half*)d_ws;                  // [4][N][32] fp16, 12.8 MB
    size_t uvT_bytes  = (size_t)N * 128 * sizeof(__half);
    size_t packed_off = (uvT_bytes + 255) & ~(size_t)255;
    size_t meta_off   = (packed_off + (size_t)M * 8 + 255) & ~(size_t)255;
    unsigned long long* packed = (unsigned long long*)((char*)d_ws + packed_off);
    unsigned long long* meta   = (unsigned long long*)((char*)d_ws + meta_off);
    const bool fields_fit = (N < (1 << 17));
    const bool use_packed =
        fields_fit && (ws_size >= meta_off + (size_t)E * 8);

    float* out_pos    = (float*)d_out;            // [N,K]
    float* out_struct = (float*)d_out + (size_t)N * KANCH;

    {
        constexpr int BM = 64;
        dim3 grid((N + BM - 1) / BM);
        pgnn_proj_kernel<<<grid, 128, 0, stream>>>(feature, W_u, b_u, W_v, b_v, uvT, N);
    }
    dim3 pgrid((N + 3) / 4);
    if (use_packed) {
        pgnn_merge_kernel<<<dim3((E + 255) / 256), 256, 0, stream>>>(
            src, dst, sp_dist, meta, E);
        pgnn_pack_kernel<<<dim3((M + 255) / 256), 256, 0, stream>>>(
            anchor_eid, meta, packed, M);
        pgnn_pass_kernel<false, true><<<pgrid, 256, 0, stream>>>(
            uvT, src, dst, sp_dist, anchor_eid, packed, W_out, b_out,
            out_pos, out_struct, N, 0);
        for (int q = 1; q < 4; ++q)
            pgnn_pass_kernel<false, false><<<pgrid, 256, 0, stream>>>(
                uvT, src, dst, sp_dist, anchor_eid, packed, W_out, b_out,
                out_pos, out_struct, N, q);
    } else {
        pgnn_pass_kernel<true, true><<<pgrid, 256, 0, stream>>>(
            uvT, src, dst, sp_dist, anchor_eid, packed, W_out, b_out,
            out_pos, out_struct, N, 0);
        for (int q = 1; q < 4; ++q)
            pgnn_pass_kernel<true, false><<<pgrid, 256, 0, stream>>>(
                uvT, src, dst, sp_dist, anchor_eid, packed, W_out, b_out,
                out_pos, out_struct, N, q);
    }
}

// Round 9
// 285.631 us; speedup vs baseline: 1.4193x; 1.0144x over previous
//
#include <hip/hip_runtime.h>
#include <hip/hip_fp16.h>
#include <hip/hip_bf16.h>

// PGNN layer for MI355X (gfx950).
//   u = feature @ W_u + b_u            [N,64]
//   v = feature @ W_v + b_v            [N,64]
//   msg[e] = v[dst[e]] + u[src[e]] * sp_dist[e]
//   msgs = relu(msg[anchor_eid]).reshape(N, K, 64)
//   out_position  = msgs @ W_out + b_out   -> [N,K]
//   out_structure = mean_k(msgs)           -> [N,64]
// N=50000, K=64, E=N*K=3.2M. d_out = out_position ++ out_structure.
//
// R9 = R8 with the projection GEMM rebuilt (edge path byte-identical).
// R8 evidence: proj = 76us top dispatch, 3.6M LDS bank conflicts (4-way on
// sB 32B-stride reads), 16% occupancy (782 blocks x 2 waves). Fix: 256-thr
// blocks (4 waves), TM=4 x TN=4+4 (two col-quads 16B-stride -> 2-way=free),
// 12 waves/CU. Edge structure unchanged: merge -> pack -> 4 L2-resident
// dim-slice passes.

#define IN_DIM 256
#define OUT_DIM 64
#define KANCH 64

typedef float vfloat4 __attribute__((ext_vector_type(4)));

// ---------------- Kernel 1: fused projection GEMM (fp32 -> fp16 uvT) -------
// uvT[4][N][32]: slice q holds u dims 16q..16q+15 at [0..15], v at [16..31].
// 256 threads as (tr = tid>>4 in 0..15 -> rows tr*4..+3; tc = tid&15 ->
// u-cols tc*4..+3 and v-cols 64+tc*4..+3).
__global__ __launch_bounds__(256) void pgnn_proj_kernel(
    const float* __restrict__ feature,
    const float* __restrict__ Wu, const float* __restrict__ bu,
    const float* __restrict__ Wv, const float* __restrict__ bv,
    __half* __restrict__ uvT, int N)
{
    constexpr int BM = 64, BK = 16, PA = 68, PB = 132;
    __shared__ float sA[BK * PA];   // sA[k][m], transposed A tile
    __shared__ float sB[BK * PB];   // sB[k][c], c in 0..127 (u | v)

    const int tid  = threadIdx.x;
    const int row0 = blockIdx.x * BM;
    const int tr   = tid >> 4;   // 0..15 -> rows tr*4..tr*4+3
    const int tc   = tid & 15;   // 0..15 -> col quads

    float accU[4][4], accV[4][4];
    #pragma unroll
    for (int i = 0; i < 4; ++i)
        #pragma unroll
        for (int j = 0; j < 4; ++j) { accU[i][j] = 0.f; accV[i][j] = 0.f; }

    for (int k0 = 0; k0 < IN_DIM; k0 += BK) {
        // Stage A tile (64 m x 16 k) transposed: 256 float4, 1 per thread.
        {
            int m  = tid >> 2, c4 = tid & 3;
            int gr = row0 + m;
            float4 va = make_float4(0.f, 0.f, 0.f, 0.f);
            if (gr < N)
                va = *reinterpret_cast<const float4*>(
                        &feature[(size_t)gr * IN_DIM + k0 + c4 * 4]);
            sA[(c4 * 4 + 0) * PA + m] = va.x;
            sA[(c4 * 4 + 1) * PA + m] = va.y;
            sA[(c4 * 4 + 2) * PA + m] = va.z;
            sA[(c4 * 4 + 3) * PA + m] = va.w;
        }
        // Stage B tile (16 k x 128 c): 512 float4, 2 per thread.
        #pragma unroll
        for (int i = 0; i < 2; ++i) {
            int f  = tid + i * 256;        // 0..511
            int kk = f >> 5, c4 = f & 31;
            float4 vb;
            if (c4 < 16)
                vb = *reinterpret_cast<const float4*>(&Wu[(k0 + kk) * OUT_DIM + c4 * 4]);
            else
                vb = *reinterpret_cast<const float4*>(&Wv[(k0 + kk) * OUT_DIM + (c4 - 16) * 4]);
            *reinterpret_cast<float4*>(&sB[kk * PB + c4 * 4]) = vb;
        }
        __syncthreads();

        #pragma unroll
        for (int k = 0; k < BK; ++k) {
            float4 a  = *reinterpret_cast<const float4*>(&sA[k * PA + tr * 4]);
            float4 b0 = *reinterpret_cast<const float4*>(&sB[k * PB + tc * 4]);
            float4 b1 = *reinterpret_cast<const float4*>(&sB[k * PB + 64 + tc * 4]);
            float av[4] = {a.x, a.y, a.z, a.w};
            float bu4[4] = {b0.x, b0.y, b0.z, b0.w};
            float bv4[4] = {b1.x, b1.y, b1.z, b1.w};
            #pragma unroll
            for (int i = 0; i < 4; ++i)
                #pragma unroll
                for (int j = 0; j < 4; ++j) {
                    accU[i][j] = fmaf(av[i], bu4[j], accU[i][j]);
                    accV[i][j] = fmaf(av[i], bv4[j], accV[i][j]);
                }
        }
        __syncthreads();
    }

    // Epilogue: bias, fp16, write into uvT slice q = tc>>2.
    const int q  = tc >> 2;
    const int i0 = (tc & 3) * 4;   // within-slice dim base
    float bU[4], bV[4];
    #pragma unroll
    for (int j = 0; j < 4; ++j) {
        bU[j] = bu[tc * 4 + j];
        bV[j] = bv[tc * 4 + j];
    }
    #pragma unroll
    for (int i = 0; i < 4; ++i) {
        int gr = row0 + tr * 4 + i;
        if (gr >= N) continue;
        __half* rowp = uvT + ((size_t)q * N + gr) * 32;
        __half2 hu0 = __floats2half2_rn(accU[i][0] + bU[0], accU[i][1] + bU[1]);
        __half2 hu1 = __floats2half2_rn(accU[i][2] + bU[2], accU[i][3] + bU[3]);
        __half2 hv0 = __floats2half2_rn(accV[i][0] + bV[0], accV[i][1] + bV[1]);
        __half2 hv1 = __floats2half2_rn(accV[i][2] + bV[2], accV[i][3] + bV[3]);
        *reinterpret_cast<__half2*>(rowp + i0)          = hu0;
        *reinterpret_cast<__half2*>(rowp + i0 + 2)      = hu1;
        *reinterpret_cast<__half2*>(rowp + 16 + i0)     = hv0;
        *reinterpret_cast<__half2*>(rowp + 16 + i0 + 2) = hv1;
    }
}

// ---------------- Kernel 2: merge (src,dst,sp16) -> edge_meta[E] 8B --------
// pk = src | dst<<17 | half(sp)<<34   (requires node ids < 2^17)
__global__ __launch_bounds__(256) void pgnn_merge_kernel(
    const int* __restrict__ src, const int* __restrict__ dst,
    const float* __restrict__ sp, unsigned long long* __restrict__ meta, int E)
{
    int i = blockIdx.x * 256 + threadIdx.x;
    if (i >= E) return;
    unsigned long long pk =
          (unsigned long long)(unsigned)__builtin_nontemporal_load(&src[i])
        | ((unsigned long long)(unsigned)__builtin_nontemporal_load(&dst[i]) << 17)
        | ((unsigned long long)__half_as_ushort(
               __float2half_rn(__builtin_nontemporal_load(&sp[i]))) << 34);
    __builtin_nontemporal_store(pk, &meta[i]);
}

// ---------------- Kernel 3: pack: packed[i] = edge_meta[aeid[i]] -----------
__global__ __launch_bounds__(256) void pgnn_pack_kernel(
    const int* __restrict__ aeid, const unsigned long long* __restrict__ meta,
    unsigned long long* __restrict__ packed, int M)
{
    int i = blockIdx.x * 256 + threadIdx.x;
    if (i >= M) return;
    int e = __builtin_nontemporal_load(&aeid[i]);
    __builtin_nontemporal_store(meta[e], &packed[i]);
}

// ---------------- Kernel 4: dim-sliced edge pass ---------------------------
// One wave per node, 4 waves/block. lane = (g = lane>>2 in 0..15, j4 = lane&3).
// Anchor k = i*16+g (i=0..3); lane covers dims q*16 + 4*j4 .. +3 via half4
// gathers. pos: dot over 4 dims + shfl_xor(1,2) over the j4 quad -> LDS ->
// coalesced store/atomic. struct: shfl_xor(4,8,16,32) over g.
// GATHER variant (fallback, any N): reads aeid->src/dst/sp directly.
template<bool GATHER, bool FIRST>
__global__ __launch_bounds__(256) void pgnn_pass_kernel(
    const __half* __restrict__ uvT,
    const int*    __restrict__ src,
    const int*    __restrict__ dst,
    const float*  __restrict__ sp_dist,
    const int*    __restrict__ aeid,
    const unsigned long long* __restrict__ packed,
    const float*  __restrict__ W_out,
    const float*  __restrict__ b_out,
    float* __restrict__ out_pos,     // [N,64]
    float* __restrict__ out_struct,  // [N,64]
    int N, int q)
{
    const int lane = threadIdx.x & 63;
    const int wv   = threadIdx.x >> 6;
    const int n    = blockIdx.x * 4 + wv;
    if (n >= N) return;   // wave-uniform

    __shared__ float posb[4][64];
    float* pb = posb[wv];

    const int j4 = lane & 3, g = lane >> 2;

    // Per-lane meta for anchor k = lane.
    int ms = 0, md = 0; float msp = 0.f;
    unsigned int mlo = 0, mhi = 0;
    if constexpr (GATHER) {
        const int e = __builtin_nontemporal_load(&aeid[(size_t)n * KANCH + lane]);
        ms = src[e]; md = dst[e]; msp = sp_dist[e];
    } else {
        unsigned long long pk =
            __builtin_nontemporal_load(&packed[(size_t)n * KANCH + lane]);
        mlo = (unsigned int)pk;
        mhi = (unsigned int)(pk >> 32);
    }

    const float4 w4 = *reinterpret_cast<const float4*>(&W_out[q * 16 + 4 * j4]);
    const __half* Uq = uvT + (size_t)q * N * 32;

    float4 acc = make_float4(0.f, 0.f, 0.f, 0.f);
    union H4 { uint2 u; __half2 h[2]; };

    #pragma unroll
    for (int i = 0; i < 4; ++i) {
        const int k = i * 16 + g;   // anchor index; meta source lane
        int ss, dd; float sp;
        if constexpr (GATHER) {
            ss = __shfl(ms, k);
            dd = __shfl(md, k);
            sp = __shfl(msp, k);
        } else {
            unsigned int lo = (unsigned int)__shfl((int)mlo, k);
            unsigned int hi = (unsigned int)__shfl((int)mhi, k);
            ss = (int)(lo & 0x1FFFFu);
            dd = (int)(((lo >> 17) | (hi << 15)) & 0x1FFFFu);
            sp = __half2float(__ushort_as_half((unsigned short)((hi >> 2) & 0xFFFFu)));
        }
        H4 uu, vv;
        uu.u = *reinterpret_cast<const uint2*>(&Uq[(size_t)ss * 32 + 4 * j4]);
        vv.u = *reinterpret_cast<const uint2*>(&Uq[(size_t)dd * 32 + 16 + 4 * j4]);
        float2 ua = __half22float2(uu.h[0]), ub = __half22float2(uu.h[1]);
        float2 va = __half22float2(vv.h[0]), vb = __half22float2(vv.h[1]);
        float m0 = fmaxf(fmaf(ua.x, sp, va.x), 0.f);
        float m1 = fmaxf(fmaf(ua.y, sp, va.y), 0.f);
        float m2 = fmaxf(fmaf(ub.x, sp, vb.x), 0.f);
        float m3 = fmaxf(fmaf(ub.y, sp, vb.y), 0.f);
        acc.x += m0; acc.y += m1; acc.z += m2; acc.w += m3;

        // pos partial for anchor k: dot over this lane's 4 dims, then the quad
        float p = fmaf(m0, w4.x, fmaf(m1, w4.y, fmaf(m2, w4.z, m3 * w4.w)));
        p += __shfl_xor(p, 1);
        p += __shfl_xor(p, 2);
        if (j4 == 0) pb[k] = p;
    }
    asm volatile("s_waitcnt lgkmcnt(0)" ::: "memory");

    const float pos = pb[lane];
    if constexpr (FIRST) {
        __builtin_nontemporal_store(pos + b_out[0],
                                    &out_pos[(size_t)n * KANCH + lane]);
    } else {
        atomicAdd(&out_pos[(size_t)n * KANCH + lane], pos);
    }

    // struct: sum acc over the 16 g-groups (lanes stride 4).
    #pragma unroll
    for (int off = 4; off <= 32; off <<= 1) {
        acc.x += __shfl_xor(acc.x, off);
        acc.y += __shfl_xor(acc.y, off);
        acc.z += __shfl_xor(acc.z, off);
        acc.w += __shfl_xor(acc.w, off);
    }
    if (lane < 4) {
        vfloat4 s = { acc.x * (1.f / KANCH), acc.y * (1.f / KANCH),
                      acc.z * (1.f / KANCH), acc.w * (1.f / KANCH) };
        __builtin_nontemporal_store(
            s, reinterpret_cast<vfloat4*>(
                   &out_struct[(size_t)n * OUT_DIM + q * 16 + 4 * lane]));
    }
}

extern "C" void kernel_launch(void* const* d_in, const int* in_sizes, int n_in,
                              void* d_out, int out_size, void* d_ws, size_t ws_size,
                              hipStream_t stream) {
    const float* feature    = (const float*)d_in[0];
    const int*   src        = (const int*)  d_in[1];
    const int*   dst        = (const int*)  d_in[2];
    const float* sp_dist    = (const float*)d_in[3];
    const int*   anchor_eid = (const int*)  d_in[4];
    // d_in[5] = dists_max: shape-only in the reference, numerically unused.
    const float* W_u   = (const float*)d_in[6];
    const float* b_u   = (const float*)d_in[7];
    const float* W_v   = (const float*)d_in[8];
    const float* b_v   = (const float*)d_in[9];
    const float* W_out = (const float*)d_in[10];
    const float* b_out = (const float*)d_in[11];

    const int N = in_sizes[0] / IN_DIM;           // 50000
    const int E = in_sizes[1];                    // 3.2M
    const int M = N * KANCH;                      // anchors

    __half* uvT = (__half*)d_ws;                  // [4][N][32] fp16, 12.8 MB
    size_t uvT_bytes  = (size_t)N * 128 * sizeof(__half);
    size_t packed_off = (uvT_bytes + 255) & ~(size_t)255;
    size_t meta_off   = (packed_off + (size_t)M * 8 + 255) & ~(size_t)255;
    unsigned long long* packed = (unsigned long long*)((char*)d_ws + packed_off);
    unsigned long long* meta   = (unsigned long long*)((char*)d_ws + meta_off);
    const bool fields_fit = (N < (1 << 17));
    const bool use_packed =
        fields_fit && (ws_size >= meta_off + (size_t)E * 8);

    float* out_pos    = (float*)d_out;            // [N,K]
    float* out_struct = (float*)d_out + (size_t)N * KANCH;

    {
        constexpr int BM = 64;
        dim3 grid((N + BM - 1) / BM);
        pgnn_proj_kernel<<<grid, 256, 0, stream>>>(feature, W_u, b_u, W_v, b_v, uvT, N);
    }
    dim3 pgrid((N + 3) / 4);
    if (use_packed) {
        pgnn_merge_kernel<<<dim3((E + 255) / 256), 256, 0, stream>>>(
            src, dst, sp_dist, meta, E);
        pgnn_pack_kernel<<<dim3((M + 255) / 256), 256, 0, stream>>>(
            anchor_eid, meta, packed, M);
        pgnn_pass_kernel<false, true><<<pgrid, 256, 0, stream>>>(
            uvT, src, dst, sp_dist, anchor_eid, packed, W_out, b_out,
            out_pos, out_struct, N, 0);
        for (int q = 1; q < 4; ++q)
            pgnn_pass_kernel<false, false><<<pgrid, 256, 0, stream>>>(
                uvT, src, dst, sp_dist, anchor_eid, packed, W_out, b_out,
                out_pos, out_struct, N, q);
    } else {
        pgnn_pass_kernel<true, true><<<pgrid, 256, 0, stream>>>(
            uvT, src, dst, sp_dist, anchor_eid, packed, W_out, b_out,
            out_pos, out_struct, N, 0);
        for (int q = 1; q < 4; ++q)
            pgnn_pass_kernel<true, false><<<pgrid, 256, 0, stream>>>(
                uvT, src, dst, sp_dist, anchor_eid, packed, W_out, b_out,
                out_pos, out_struct, N, q);
    }
}

// Round 11
// 268.280 us; speedup vs baseline: 1.5111x; 1.0647x over previous
//
#include <hip/hip_runtime.h>
#include <hip/hip_fp16.h>
#include <hip/hip_bf16.h>

// PGNN layer for MI355X (gfx950).
//   u = feature @ W_u + b_u ; v = feature @ W_v + b_v       [N,64] each
//   msg[e] = v[dst[e]] + u[src[e]] * sp_dist[e]
//   msgs = relu(msg[anchor_eid]) -> [N,K,64]
//   out_position = msgs @ W_out + b_out  [N,K];  out_structure = mean_k [N,64]
// N=50000, K=64, E=3.2M. d_out = out_position ++ out_structure.
//
// R11 = R10 resubmitted (infra failure, never measured).
// R10 changes vs R9 (evidence: proj 66us = barrier-exposed staging latency,
// VALUBusy 36%, conflicts already fixed; pack ~53us independent of proj but
// stream-serialized; 4 pass launches pay 3 extra gaps):
//  1. proj double-buffered LDS staging (reg prefetch, 1 barrier/step)
//  2. pack fused into the proj launch (blockIdx branch) - overlaps pipes
//  3. passes q=1..3 fused into one launch (q = blockIdx / nblk)

#define IN_DIM 256
#define OUT_DIM 64
#define KANCH 64

typedef float vfloat4 __attribute__((ext_vector_type(4)));

// ---------------- merge: (src,dst,sp16) -> edge_meta[E] 8B -----------------
// pk = src | dst<<17 | half(sp)<<34   (requires node ids < 2^17)
__global__ __launch_bounds__(256) void pgnn_merge_kernel(
    const int* __restrict__ src, const int* __restrict__ dst,
    const float* __restrict__ sp, unsigned long long* __restrict__ meta, int E)
{
    int i = blockIdx.x * 256 + threadIdx.x;
    if (i >= E) return;
    unsigned long long pk =
          (unsigned long long)(unsigned)__builtin_nontemporal_load(&src[i])
        | ((unsigned long long)(unsigned)__builtin_nontemporal_load(&dst[i]) << 17)
        | ((unsigned long long)__half_as_ushort(
               __float2half_rn(__builtin_nontemporal_load(&sp[i]))) << 34);
    __builtin_nontemporal_store(pk, &meta[i]);
}

// ---------------- fused: proj GEMM (dbuf) + pack ---------------------------
// Blocks [0, projBlocks): proj tile BM=64. Blocks [projBlocks, +packBlocks):
// grid-stride pack packed[i] = meta[aeid[i]], batched x8 for MLP.
// uvT[4][N][32]: slice q holds u dims 16q.. at [0..15], v at [16..31].
#define PAa 68
#define PBb 132
#define TILEF (16 * PAa + 16 * PBb)   // floats per buffer = 3200
__global__ __launch_bounds__(256) void pgnn_fused_kernel(
    const float* __restrict__ feature,
    const float* __restrict__ Wu, const float* __restrict__ bu,
    const float* __restrict__ Wv, const float* __restrict__ bv,
    __half* __restrict__ uvT,
    const int* __restrict__ aeid,
    const unsigned long long* __restrict__ meta,
    unsigned long long* __restrict__ packed,
    int N, int M, int projBlocks, int packBlocks)
{
    __shared__ float smem[2 * TILEF];
    const int tid = threadIdx.x;

    if ((int)blockIdx.x < projBlocks) {
        // ---------------- proj body (double-buffered) ----------------
        const int row0 = blockIdx.x * 64;
        const int tr = tid >> 4;     // 0..15 -> rows tr*4..+3
        const int tc = tid & 15;     // 0..15 -> col quads (u: tc*4, v: 64+tc*4)
        const int mA = tid >> 2, c4A = tid & 3;      // A-staging coords
        const int grA = row0 + mA;

        float accU[4][4], accV[4][4];
        #pragma unroll
        for (int i = 0; i < 4; ++i)
            #pragma unroll
            for (int j = 0; j < 4; ++j) { accU[i][j] = 0.f; accV[i][j] = 0.f; }

        float4 ra, rb0, rb1;
        auto load_tile = [&](int k0) {
            ra = make_float4(0.f, 0.f, 0.f, 0.f);
            if (grA < N)
                ra = *reinterpret_cast<const float4*>(
                        &feature[(size_t)grA * IN_DIM + k0 + c4A * 4]);
            {
                int f = tid, kk = f >> 5, c4 = f & 31;
                rb0 = (c4 < 16)
                    ? *reinterpret_cast<const float4*>(&Wu[(k0 + kk) * OUT_DIM + c4 * 4])
                    : *reinterpret_cast<const float4*>(&Wv[(k0 + kk) * OUT_DIM + (c4 - 16) * 4]);
            }
            {
                int f = tid + 256, kk = f >> 5, c4 = f & 31;
                rb1 = (c4 < 16)
                    ? *reinterpret_cast<const float4*>(&Wu[(k0 + kk) * OUT_DIM + c4 * 4])
                    : *reinterpret_cast<const float4*>(&Wv[(k0 + kk) * OUT_DIM + (c4 - 16) * 4]);
            }
        };
        auto store_tile = [&](float* buf) {
            buf[(c4A * 4 + 0) * PAa + mA] = ra.x;
            buf[(c4A * 4 + 1) * PAa + mA] = ra.y;
            buf[(c4A * 4 + 2) * PAa + mA] = ra.z;
            buf[(c4A * 4 + 3) * PAa + mA] = ra.w;
            float* sB = buf + 16 * PAa;
            {
                int f = tid, kk = f >> 5, c4 = f & 31;
                *reinterpret_cast<float4*>(&sB[kk * PBb + c4 * 4]) = rb0;
            }
            {
                int f = tid + 256, kk = f >> 5, c4 = f & 31;
                *reinterpret_cast<float4*>(&sB[kk * PBb + c4 * 4]) = rb1;
            }
        };

        load_tile(0);
        store_tile(smem);
        __syncthreads();

        for (int s = 0; s < 16; ++s) {
            const int cur = s & 1;
            if (s < 15) load_tile((s + 1) * 16);
            const float* buf = smem + cur * TILEF;
            const float* sB  = buf + 16 * PAa;
            #pragma unroll
            for (int k = 0; k < 16; ++k) {
                float4 a  = *reinterpret_cast<const float4*>(&buf[k * PAa + tr * 4]);
                float4 b0 = *reinterpret_cast<const float4*>(&sB[k * PBb + tc * 4]);
                float4 b1 = *reinterpret_cast<const float4*>(&sB[k * PBb + 64 + tc * 4]);
                float av[4]  = {a.x, a.y, a.z, a.w};
                float bu4[4] = {b0.x, b0.y, b0.z, b0.w};
                float bv4[4] = {b1.x, b1.y, b1.z, b1.w};
                #pragma unroll
                for (int i = 0; i < 4; ++i)
                    #pragma unroll
                    for (int j = 0; j < 4; ++j) {
                        accU[i][j] = fmaf(av[i], bu4[j], accU[i][j]);
                        accV[i][j] = fmaf(av[i], bv4[j], accV[i][j]);
                    }
            }
            if (s < 15) store_tile(smem + (cur ^ 1) * TILEF);
            __syncthreads();
        }

        // Epilogue: bias, fp16, write uvT slice q = tc>>2.
        const int q  = tc >> 2;
        const int i0 = (tc & 3) * 4;
        float bU[4], bV[4];
        #pragma unroll
        for (int j = 0; j < 4; ++j) { bU[j] = bu[tc * 4 + j]; bV[j] = bv[tc * 4 + j]; }
        #pragma unroll
        for (int i = 0; i < 4; ++i) {
            int gr = row0 + tr * 4 + i;
            if (gr >= N) continue;
            __half* rowp = uvT + ((size_t)q * N + gr) * 32;
            __half2 hu0 = __floats2half2_rn(accU[i][0] + bU[0], accU[i][1] + bU[1]);
            __half2 hu1 = __floats2half2_rn(accU[i][2] + bU[2], accU[i][3] + bU[3]);
            __half2 hv0 = __floats2half2_rn(accV[i][0] + bV[0], accV[i][1] + bV[1]);
            __half2 hv1 = __floats2half2_rn(accV[i][2] + bV[2], accV[i][3] + bV[3]);
            *reinterpret_cast<__half2*>(rowp + i0)          = hu0;
            *reinterpret_cast<__half2*>(rowp + i0 + 2)      = hu1;
            *reinterpret_cast<__half2*>(rowp + 16 + i0)     = hv0;
            *reinterpret_cast<__half2*>(rowp + 16 + i0 + 2) = hv1;
        }
    } else {
        // ---------------- pack body (batched x8 grid-stride) ----------------
        const int stride = packBlocks * 256;
        int i = (blockIdx.x - projBlocks) * 256 + tid;
        while (i + 7 * stride < M) {
            int e[8];
            #pragma unroll
            for (int b = 0; b < 8; ++b)
                e[b] = __builtin_nontemporal_load(&aeid[i + b * stride]);
            unsigned long long m[8];
            #pragma unroll
            for (int b = 0; b < 8; ++b) m[b] = meta[e[b]];
            #pragma unroll
            for (int b = 0; b < 8; ++b)
                __builtin_nontemporal_store(m[b], &packed[i + b * stride]);
            i += 8 * stride;
        }
        for (; i < M; i += stride) {
            int e = __builtin_nontemporal_load(&aeid[i]);
            __builtin_nontemporal_store(meta[e], &packed[i]);
        }
    }
}

// ---------------- dim-sliced edge pass -------------------------------------
// One wave per node, 4 waves/block. lane = (g = lane>>2, j4 = lane&3).
// MULTIQ: q = 1 + blockIdx.x / nblk (passes 1..3 in one launch, atomic).
// Else q = qArg (pass 0, plain store of pos + b_out).
template<bool GATHER, bool FIRST, bool MULTIQ>
__global__ __launch_bounds__(256) void pgnn_pass_kernel(
    const __half* __restrict__ uvT,
    const int*    __restrict__ src,
    const int*    __restrict__ dst,
    const float*  __restrict__ sp_dist,
    const int*    __restrict__ aeid,
    const unsigned long long* __restrict__ packed,
    const float*  __restrict__ W_out,
    const float*  __restrict__ b_out,
    float* __restrict__ out_pos,     // [N,64]
    float* __restrict__ out_struct,  // [N,64]
    int N, int qArg, int nblk)
{
    int q, blk;
    if constexpr (MULTIQ) { q = 1 + blockIdx.x / nblk; blk = blockIdx.x % nblk; }
    else                  { q = qArg;                  blk = blockIdx.x; }

    const int lane = threadIdx.x & 63;
    const int wv   = threadIdx.x >> 6;
    const int n    = blk * 4 + wv;
    if (n >= N) return;   // wave-uniform

    __shared__ float posb[4][64];
    float* pb = posb[wv];

    const int j4 = lane & 3, g = lane >> 2;

    int ms = 0, md = 0; float msp = 0.f;
    unsigned int mlo = 0, mhi = 0;
    if constexpr (GATHER) {
        const int e = __builtin_nontemporal_load(&aeid[(size_t)n * KANCH + lane]);
        ms = src[e]; md = dst[e]; msp = sp_dist[e];
    } else {
        unsigned long long pk =
            __builtin_nontemporal_load(&packed[(size_t)n * KANCH + lane]);
        mlo = (unsigned int)pk;
        mhi = (unsigned int)(pk >> 32);
    }

    const float4 w4 = *reinterpret_cast<const float4*>(&W_out[q * 16 + 4 * j4]);
    const __half* Uq = uvT + (size_t)q * N * 32;

    float4 acc = make_float4(0.f, 0.f, 0.f, 0.f);
    union H4 { uint2 u; __half2 h[2]; };

    #pragma unroll
    for (int i = 0; i < 4; ++i) {
        const int k = i * 16 + g;
        int ss, dd; float sp;
        if constexpr (GATHER) {
            ss = __shfl(ms, k);
            dd = __shfl(md, k);
            sp = __shfl(msp, k);
        } else {
            unsigned int lo = (unsigned int)__shfl((int)mlo, k);
            unsigned int hi = (unsigned int)__shfl((int)mhi, k);
            ss = (int)(lo & 0x1FFFFu);
            dd = (int)(((lo >> 17) | (hi << 15)) & 0x1FFFFu);
            sp = __half2float(__ushort_as_half((unsigned short)((hi >> 2) & 0xFFFFu)));
        }
        H4 uu, vv;
        uu.u = *reinterpret_cast<const uint2*>(&Uq[(size_t)ss * 32 + 4 * j4]);
        vv.u = *reinterpret_cast<const uint2*>(&Uq[(size_t)dd * 32 + 16 + 4 * j4]);
        float2 ua = __half22float2(uu.h[0]), ub = __half22float2(uu.h[1]);
        float2 va = __half22float2(vv.h[0]), vb = __half22float2(vv.h[1]);
        float m0 = fmaxf(fmaf(ua.x, sp, va.x), 0.f);
        float m1 = fmaxf(fmaf(ua.y, sp, va.y), 0.f);
        float m2 = fmaxf(fmaf(ub.x, sp, vb.x), 0.f);
        float m3 = fmaxf(fmaf(ub.y, sp, vb.y), 0.f);
        acc.x += m0; acc.y += m1; acc.z += m2; acc.w += m3;

        float p = fmaf(m0, w4.x, fmaf(m1, w4.y, fmaf(m2, w4.z, m3 * w4.w)));
        p += __shfl_xor(p, 1);
        p += __shfl_xor(p, 2);
        if (j4 == 0) pb[k] = p;
    }
    asm volatile("s_waitcnt lgkmcnt(0)" ::: "memory");

    const float pos = pb[lane];
    if constexpr (FIRST) {
        __builtin_nontemporal_store(pos + b_out[0],
                                    &out_pos[(size_t)n * KANCH + lane]);
    } else {
        atomicAdd(&out_pos[(size_t)n * KANCH + lane], pos);
    }

    #pragma unroll
    for (int off = 4; off <= 32; off <<= 1) {
        acc.x += __shfl_xor(acc.x, off);
        acc.y += __shfl_xor(acc.y, off);
        acc.z += __shfl_xor(acc.z, off);
        acc.w += __shfl_xor(acc.w, off);
    }
    if (lane < 4) {
        vfloat4 s = { acc.x * (1.f / KANCH), acc.y * (1.f / KANCH),
                      acc.z * (1.f / KANCH), acc.w * (1.f / KANCH) };
        __builtin_nontemporal_store(
            s, reinterpret_cast<vfloat4*>(
                   &out_struct[(size_t)n * OUT_DIM + q * 16 + 4 * lane]));
    }
}

extern "C" void kernel_launch(void* const* d_in, const int* in_sizes, int n_in,
                              void* d_out, int out_size, void* d_ws, size_t ws_size,
                              hipStream_t stream) {
    const float* feature    = (const float*)d_in[0];
    const int*   src        = (const int*)  d_in[1];
    const int*   dst        = (const int*)  d_in[2];
    const float* sp_dist    = (const float*)d_in[3];
    const int*   anchor_eid = (const int*)  d_in[4];
    // d_in[5] = dists_max: shape-only, numerically unused.
    const float* W_u   = (const float*)d_in[6];
    const float* b_u   = (const float*)d_in[7];
    const float* W_v   = (const float*)d_in[8];
    const float* b_v   = (const float*)d_in[9];
    const float* W_out = (const float*)d_in[10];
    const float* b_out = (const float*)d_in[11];

    const int N = in_sizes[0] / IN_DIM;           // 50000
    const int E = in_sizes[1];                    // 3.2M
    const int M = N * KANCH;

    __half* uvT = (__half*)d_ws;                  // [4][N][32] fp16, 12.8 MB
    size_t uvT_bytes  = (size_t)N * 128 * sizeof(__half);
    size_t packed_off = (uvT_bytes + 255) & ~(size_t)255;
    size_t meta_off   = (packed_off + (size_t)M * 8 + 255) & ~(size_t)255;
    unsigned long long* packed = (unsigned long long*)((char*)d_ws + packed_off);
    unsigned long long* meta   = (unsigned long long*)((char*)d_ws + meta_off);
    const bool fields_fit = (N < (1 << 17));
    const bool use_packed = fields_fit && (ws_size >= meta_off + (size_t)E * 8);

    float* out_pos    = (float*)d_out;            // [N,K]
    float* out_struct = (float*)d_out + (size_t)N * KANCH;

    const int projBlocks = (N + 63) / 64;         // 782
    const int nblk = (N + 3) / 4;                 // 12500

    if (use_packed) {
        pgnn_merge_kernel<<<dim3((E + 255) / 256), 256, 0, stream>>>(
            src, dst, sp_dist, meta, E);
        const int packBlocks = 512;
        pgnn_fused_kernel<<<dim3(projBlocks + packBlocks), 256, 0, stream>>>(
            feature, W_u, b_u, W_v, b_v, uvT, anchor_eid, meta, packed,
            N, M, projBlocks, packBlocks);
        pgnn_pass_kernel<false, true, false><<<dim3(nblk), 256, 0, stream>>>(
            uvT, src, dst, sp_dist, anchor_eid, packed, W_out, b_out,
            out_pos, out_struct, N, 0, nblk);
        pgnn_pass_kernel<false, false, true><<<dim3(3 * nblk), 256, 0, stream>>>(
            uvT, src, dst, sp_dist, anchor_eid, packed, W_out, b_out,
            out_pos, out_struct, N, 0, nblk);
    } else {
        pgnn_fused_kernel<<<dim3(projBlocks), 256, 0, stream>>>(
            feature, W_u, b_u, W_v, b_v, uvT, anchor_eid, meta, packed,
            N, M, projBlocks, 0);
        pgnn_pass_kernel<true, true, false><<<dim3(nblk), 256, 0, stream>>>(
            uvT, src, dst, sp_dist, anchor_eid, packed, W_out, b_out,
            out_pos, out_struct, N, 0, nblk);
        for (int q = 1; q < 4; ++q)
            pgnn_pass_kernel<true, false, false><<<dim3(nblk), 256, 0, stream>>>(
                uvT, src, dst, sp_dist, anchor_eid, packed, W_out, b_out,
                out_pos, out_struct, N, q, nblk);
    }
}

// Round 12
// 267.089 us; speedup vs baseline: 1.5178x; 1.0045x over previous
//
#include <hip/hip_runtime.h>
#include <hip/hip_fp16.h>
#include <hip/hip_bf16.h>

// PGNN layer for MI355X (gfx950).
//   u = feature @ W_u + b_u ; v = feature @ W_v + b_v       [N,64] each
//   msg[e] = v[dst[e]] + u[src[e]] * sp_dist[e]
//   msgs = relu(msg[anchor_eid]) -> [N,K,64]
//   out_position = msgs @ W_out + b_out  [N,K];  out_structure = mean_k [N,64]
// N=50000, K=64, E=3.2M. d_out = out_position ++ out_structure.
//
// R12 vs R11 (evidence: multiq pass 125us with FETCH 80MB / VALU 35% / Occ 78%
// -> gather-address-divergence-bound, ~1 L2 line per lane-load per cycle;
// 8 gather instrs/wave x 64 lanes = 512 cyc/wave matches 125us exactly):
//  1. passes use 16B dwordx4 gathers: 2 lanes/anchor (h=0,1), 4 gather
//     instrs/wave instead of 8 -> predict pass time ~halves
//  2. all 4 dim-slices in ONE launch, all-atomic pos; out_pos pre-init to
//     b_out fused into the merge launch
//  3. fused proj(dbuf)+pack kernel unchanged

#define IN_DIM 256
#define OUT_DIM 64
#define KANCH 64

typedef float vfloat4 __attribute__((ext_vector_type(4)));

// ---------------- merge + pos-init (fused launch) --------------------------
// Blocks [0, mergeBlocks): meta[i] = src|dst<<17|half(sp)<<34 (ids < 2^17).
// Blocks [mergeBlocks, ...): out_pos[0..M) = b_out[0] (float4 stores).
__global__ __launch_bounds__(256) void pgnn_merge_init_kernel(
    const int* __restrict__ src, const int* __restrict__ dst,
    const float* __restrict__ sp, unsigned long long* __restrict__ meta, int E,
    float* __restrict__ out_pos, const float* __restrict__ b_out, int M,
    int mergeBlocks)
{
    if ((int)blockIdx.x < mergeBlocks) {
        int i = blockIdx.x * 256 + threadIdx.x;
        if (i >= E) return;
        unsigned long long pk =
              (unsigned long long)(unsigned)__builtin_nontemporal_load(&src[i])
            | ((unsigned long long)(unsigned)__builtin_nontemporal_load(&dst[i]) << 17)
            | ((unsigned long long)__half_as_ushort(
                   __float2half_rn(__builtin_nontemporal_load(&sp[i]))) << 34);
        __builtin_nontemporal_store(pk, &meta[i]);
    } else {
        const float bo = b_out[0];
        int i4 = (blockIdx.x - mergeBlocks) * 256 + threadIdx.x;
        int base = i4 * 4;
        if (base + 3 < M) {
            vfloat4 s = {bo, bo, bo, bo};
            __builtin_nontemporal_store(s, reinterpret_cast<vfloat4*>(&out_pos[base]));
        } else {
            for (int i = base; i < M; ++i) out_pos[i] = bo;
        }
    }
}

// ---------------- fused: proj GEMM (dbuf) + pack ---------------------------
// Blocks [0, projBlocks): proj tile BM=64. Blocks [projBlocks, +packBlocks):
// grid-stride pack packed[i] = meta[aeid[i]], batched x8 for MLP.
// uvT[4][N][32]: slice q holds u dims 16q.. at [0..15], v at [16..31].
#define PAa 68
#define PBb 132
#define TILEF (16 * PAa + 16 * PBb)   // floats per buffer = 3200
__global__ __launch_bounds__(256) void pgnn_fused_kernel(
    const float* __restrict__ feature,
    const float* __restrict__ Wu, const float* __restrict__ bu,
    const float* __restrict__ Wv, const float* __restrict__ bv,
    __half* __restrict__ uvT,
    const int* __restrict__ aeid,
    const unsigned long long* __restrict__ meta,
    unsigned long long* __restrict__ packed,
    int N, int M, int projBlocks, int packBlocks)
{
    __shared__ float smem[2 * TILEF];
    const int tid = threadIdx.x;

    if ((int)blockIdx.x < projBlocks) {
        const int row0 = blockIdx.x * 64;
        const int tr = tid >> 4;     // 0..15 -> rows tr*4..+3
        const int tc = tid & 15;     // 0..15 -> col quads (u: tc*4, v: 64+tc*4)
        const int mA = tid >> 2, c4A = tid & 3;      // A-staging coords
        const int grA = row0 + mA;

        float accU[4][4], accV[4][4];
        #pragma unroll
        for (int i = 0; i < 4; ++i)
            #pragma unroll
            for (int j = 0; j < 4; ++j) { accU[i][j] = 0.f; accV[i][j] = 0.f; }

        float4 ra, rb0, rb1;
        auto load_tile = [&](int k0) {
            ra = make_float4(0.f, 0.f, 0.f, 0.f);
            if (grA < N)
                ra = *reinterpret_cast<const float4*>(
                        &feature[(size_t)grA * IN_DIM + k0 + c4A * 4]);
            {
                int f = tid, kk = f >> 5, c4 = f & 31;
                rb0 = (c4 < 16)
                    ? *reinterpret_cast<const float4*>(&Wu[(k0 + kk) * OUT_DIM + c4 * 4])
                    : *reinterpret_cast<const float4*>(&Wv[(k0 + kk) * OUT_DIM + (c4 - 16) * 4]);
            }
            {
                int f = tid + 256, kk = f >> 5, c4 = f & 31;
                rb1 = (c4 < 16)
                    ? *reinterpret_cast<const float4*>(&Wu[(k0 + kk) * OUT_DIM + c4 * 4])
                    : *reinterpret_cast<const float4*>(&Wv[(k0 + kk) * OUT_DIM + (c4 - 16) * 4]);
            }
        };
        auto store_tile = [&](float* buf) {
            buf[(c4A * 4 + 0) * PAa + mA] = ra.x;
            buf[(c4A * 4 + 1) * PAa + mA] = ra.y;
            buf[(c4A * 4 + 2) * PAa + mA] = ra.z;
            buf[(c4A * 4 + 3) * PAa + mA] = ra.w;
            float* sB = buf + 16 * PAa;
            {
                int f = tid, kk = f >> 5, c4 = f & 31;
                *reinterpret_cast<float4*>(&sB[kk * PBb + c4 * 4]) = rb0;
            }
            {
                int f = tid + 256, kk = f >> 5, c4 = f & 31;
                *reinterpret_cast<float4*>(&sB[kk * PBb + c4 * 4]) = rb1;
            }
        };

        load_tile(0);
        store_tile(smem);
        __syncthreads();

        for (int s = 0; s < 16; ++s) {
            const int cur = s & 1;
            if (s < 15) load_tile((s + 1) * 16);
            const float* buf = smem + cur * TILEF;
            const float* sB  = buf + 16 * PAa;
            #pragma unroll
            for (int k = 0; k < 16; ++k) {
                float4 a  = *reinterpret_cast<const float4*>(&buf[k * PAa + tr * 4]);
                float4 b0 = *reinterpret_cast<const float4*>(&sB[k * PBb + tc * 4]);
                float4 b1 = *reinterpret_cast<const float4*>(&sB[k * PBb + 64 + tc * 4]);
                float av[4]  = {a.x, a.y, a.z, a.w};
                float bu4[4] = {b0.x, b0.y, b0.z, b0.w};
                float bv4[4] = {b1.x, b1.y, b1.z, b1.w};
                #pragma unroll
                for (int i = 0; i < 4; ++i)
                    #pragma unroll
                    for (int j = 0; j < 4; ++j) {
                        accU[i][j] = fmaf(av[i], bu4[j], accU[i][j]);
                        accV[i][j] = fmaf(av[i], bv4[j], accV[i][j]);
                    }
            }
            if (s < 15) store_tile(smem + (cur ^ 1) * TILEF);
            __syncthreads();
        }

        const int q  = tc >> 2;
        const int i0 = (tc & 3) * 4;
        float bU[4], bV[4];
        #pragma unroll
        for (int j = 0; j < 4; ++j) { bU[j] = bu[tc * 4 + j]; bV[j] = bv[tc * 4 + j]; }
        #pragma unroll
        for (int i = 0; i < 4; ++i) {
            int gr = row0 + tr * 4 + i;
            if (gr >= N) continue;
            __half* rowp = uvT + ((size_t)q * N + gr) * 32;
            __half2 hu0 = __floats2half2_rn(accU[i][0] + bU[0], accU[i][1] + bU[1]);
            __half2 hu1 = __floats2half2_rn(accU[i][2] + bU[2], accU[i][3] + bU[3]);
            __half2 hv0 = __floats2half2_rn(accV[i][0] + bV[0], accV[i][1] + bV[1]);
            __half2 hv1 = __floats2half2_rn(accV[i][2] + bV[2], accV[i][3] + bV[3]);
            *reinterpret_cast<__half2*>(rowp + i0)          = hu0;
            *reinterpret_cast<__half2*>(rowp + i0 + 2)      = hu1;
            *reinterpret_cast<__half2*>(rowp + 16 + i0)     = hv0;
            *reinterpret_cast<__half2*>(rowp + 16 + i0 + 2) = hv1;
        }
    } else {
        const int stride = packBlocks * 256;
        int i = (blockIdx.x - projBlocks) * 256 + tid;
        while (i + 7 * stride < M) {
            int e[8];
            #pragma unroll
            for (int b = 0; b < 8; ++b)
                e[b] = __builtin_nontemporal_load(&aeid[i + b * stride]);
            unsigned long long m[8];
            #pragma unroll
            for (int b = 0; b < 8; ++b) m[b] = meta[e[b]];
            #pragma unroll
            for (int b = 0; b < 8; ++b)
                __builtin_nontemporal_store(m[b], &packed[i + b * stride]);
            i += 8 * stride;
        }
        for (; i < M; i += stride) {
            int e = __builtin_nontemporal_load(&aeid[i]);
            __builtin_nontemporal_store(meta[e], &packed[i]);
        }
    }
}

// ---------------- all-slice edge pass (4 qs in one launch) -----------------
// q = blockIdx/nblk. One wave per node, 4 waves/block.
// lane = (g = lane>>1 in 0..31, h = lane&1). Anchor k = i*32+g (i=0..1);
// lane covers dims q*16 + h*8 .. +7 via ONE dwordx4 u-gather + ONE v-gather.
// pos: 8-dim dot in-lane + shfl_xor(1) + LDS + atomicAdd (out_pos pre-init
// to b_out). struct: 5-level shfl tree over g, lanes 0/1 store 8 dims each.
template<bool GATHER>
__global__ __launch_bounds__(256) void pgnn_pass4_kernel(
    const __half* __restrict__ uvT,
    const int*    __restrict__ src,
    const int*    __restrict__ dst,
    const float*  __restrict__ sp_dist,
    const int*    __restrict__ aeid,
    const unsigned long long* __restrict__ packed,
    const float*  __restrict__ W_out,
    float* __restrict__ out_pos,     // [N,64], pre-initialized to b_out
    float* __restrict__ out_struct,  // [N,64]
    int N, int nblk)
{
    const int q   = blockIdx.x / nblk;       // 0..3
    const int blk = blockIdx.x - q * nblk;
    const int lane = threadIdx.x & 63;
    const int wv   = threadIdx.x >> 6;
    const int n    = blk * 4 + wv;
    if (n >= N) return;   // wave-uniform

    __shared__ float posb[4][64];
    float* pb = posb[wv];

    const int g = lane >> 1, h = lane & 1;

    // Per-lane meta for anchor k = lane (pre-unpacked, then shfl'd).
    int ms, md; float msp;
    if constexpr (GATHER) {
        const int e = __builtin_nontemporal_load(&aeid[(size_t)n * KANCH + lane]);
        ms = src[e]; md = dst[e]; msp = sp_dist[e];
    } else {
        unsigned long long pk =
            __builtin_nontemporal_load(&packed[(size_t)n * KANCH + lane]);
        unsigned lo = (unsigned)pk, hi = (unsigned)(pk >> 32);
        ms = (int)(lo & 0x1FFFFu);
        md = (int)(((lo >> 17) | (hi << 15)) & 0x1FFFFu);
        msp = __half2float(__ushort_as_half((unsigned short)((hi >> 2) & 0xFFFFu)));
    }

    const float4 wa = *reinterpret_cast<const float4*>(&W_out[q * 16 + h * 8]);
    const float4 wb = *reinterpret_cast<const float4*>(&W_out[q * 16 + h * 8 + 4]);

    const __half* Uq = uvT + (size_t)q * N * 32;

    float sacc[8];
    #pragma unroll
    for (int j = 0; j < 8; ++j) sacc[j] = 0.f;

    union H8 { uint4 u4; __half2 h2[4]; };

    #pragma unroll
    for (int i = 0; i < 2; ++i) {
        const int k = i * 32 + g;
        const int   ss = __shfl(ms, k);
        const int   dd = __shfl(md, k);
        const float sp = __shfl(msp, k);

        H8 uu, vv;
        uu.u4 = *reinterpret_cast<const uint4*>(&Uq[(size_t)ss * 32 + h * 8]);
        vv.u4 = *reinterpret_cast<const uint4*>(&Uq[(size_t)dd * 32 + 16 + h * 8]);

        float m[8];
        #pragma unroll
        for (int j2 = 0; j2 < 4; ++j2) {
            float2 uf = __half22float2(uu.h2[j2]);
            float2 vf = __half22float2(vv.h2[j2]);
            m[2 * j2]     = fmaxf(fmaf(uf.x, sp, vf.x), 0.f);
            m[2 * j2 + 1] = fmaxf(fmaf(uf.y, sp, vf.y), 0.f);
        }
        #pragma unroll
        for (int j = 0; j < 8; ++j) sacc[j] += m[j];

        float p = fmaf(m[0], wa.x, fmaf(m[1], wa.y, fmaf(m[2], wa.z,
                  fmaf(m[3], wa.w, fmaf(m[4], wb.x, fmaf(m[5], wb.y,
                  fmaf(m[6], wb.z, m[7] * wb.w)))))));
        p += __shfl_xor(p, 1);
        if (h == 0) pb[k] = p;
    }
    asm volatile("s_waitcnt lgkmcnt(0)" ::: "memory");

    atomicAdd(&out_pos[(size_t)n * KANCH + lane], pb[lane]);

    // struct: reduce over the 32 g-groups (bits 1..5 of lane).
    #pragma unroll
    for (int off = 2; off <= 32; off <<= 1)
        #pragma unroll
        for (int j = 0; j < 8; ++j)
            sacc[j] += __shfl_xor(sacc[j], off);

    if (lane < 2) {
        const float r = 1.f / (float)KANCH;
        vfloat4 s0 = { sacc[0] * r, sacc[1] * r, sacc[2] * r, sacc[3] * r };
        vfloat4 s1 = { sacc[4] * r, sacc[5] * r, sacc[6] * r, sacc[7] * r };
        float* op = &out_struct[(size_t)n * OUT_DIM + q * 16 + h * 8];
        __builtin_nontemporal_store(s0, reinterpret_cast<vfloat4*>(op));
        __builtin_nontemporal_store(s1, reinterpret_cast<vfloat4*>(op + 4));
    }
}

extern "C" void kernel_launch(void* const* d_in, const int* in_sizes, int n_in,
                              void* d_out, int out_size, void* d_ws, size_t ws_size,
                              hipStream_t stream) {
    const float* feature    = (const float*)d_in[0];
    const int*   src        = (const int*)  d_in[1];
    const int*   dst        = (const int*)  d_in[2];
    const float* sp_dist    = (const float*)d_in[3];
    const int*   anchor_eid = (const int*)  d_in[4];
    // d_in[5] = dists_max: shape-only, numerically unused.
    const float* W_u   = (const float*)d_in[6];
    const float* b_u   = (const float*)d_in[7];
    const float* W_v   = (const float*)d_in[8];
    const float* b_v   = (const float*)d_in[9];
    const float* W_out = (const float*)d_in[10];
    const float* b_out = (const float*)d_in[11];

    const int N = in_sizes[0] / IN_DIM;           // 50000
    const int E = in_sizes[1];                    // 3.2M
    const int M = N * KANCH;

    __half* uvT = (__half*)d_ws;                  // [4][N][32] fp16, 12.8 MB
    size_t uvT_bytes  = (size_t)N * 128 * sizeof(__half);
    size_t packed_off = (uvT_bytes + 255) & ~(size_t)255;
    size_t meta_off   = (packed_off + (size_t)M * 8 + 255) & ~(size_t)255;
    unsigned long long* packed = (unsigned long long*)((char*)d_ws + packed_off);
    unsigned long long* meta   = (unsigned long long*)((char*)d_ws + meta_off);
    const bool fields_fit = (N < (1 << 17));
    const bool use_packed = fields_fit && (ws_size >= meta_off + (size_t)E * 8);

    float* out_pos    = (float*)d_out;            // [N,K]
    float* out_struct = (float*)d_out + (size_t)N * KANCH;

    const int projBlocks = (N + 63) / 64;         // 782
    const int nblk = (N + 3) / 4;                 // 12500
    const int initBlocks = ((M + 3) / 4 + 255) / 256;

    if (use_packed) {
        const int mergeBlocks = (E + 255) / 256;
        pgnn_merge_init_kernel<<<dim3(mergeBlocks + initBlocks), 256, 0, stream>>>(
            src, dst, sp_dist, meta, E, out_pos, b_out, M, mergeBlocks);
        const int packBlocks = 512;
        pgnn_fused_kernel<<<dim3(projBlocks + packBlocks), 256, 0, stream>>>(
            feature, W_u, b_u, W_v, b_v, uvT, anchor_eid, meta, packed,
            N, M, projBlocks, packBlocks);
        pgnn_pass4_kernel<false><<<dim3(4 * nblk), 256, 0, stream>>>(
            uvT, src, dst, sp_dist, anchor_eid, packed, W_out,
            out_pos, out_struct, N, nblk);
    } else {
        // Fallback: standalone init (mergeBlocks = 0), proj only, direct gather.
        pgnn_merge_init_kernel<<<dim3(initBlocks), 256, 0, stream>>>(
            src, dst, sp_dist, meta, 0, out_pos, b_out, M, 0);
        pgnn_fused_kernel<<<dim3(projBlocks), 256, 0, stream>>>(
            feature, W_u, b_u, W_v, b_v, uvT, anchor_eid, meta, packed,
            N, M, projBlocks, 0);
        pgnn_pass4_kernel<true><<<dim3(4 * nblk), 256, 0, stream>>>(
            uvT, src, dst, sp_dist, anchor_eid, packed, W_out,
            out_pos, out_struct, N, nblk);
    }
}